// Round 1
// baseline (3997.829 us; speedup 1.0000x reference)
//
#include <hip/hip_runtime.h>
#include <cstdint>
#include <cstddef>

#define BB 64
#define TT 512
#define II 256
#define HH 256
#define GG 768   // 3*H

__device__ __forceinline__ float sigf(float x)       { return 1.f / (1.f + __expf(-x)); }
__device__ __forceinline__ float tanh_fast(float x)  { return 1.f - 2.f / (__expf(2.f * x) + 1.f); }

// ---------------------------------------------------------------------------
// Kernel A: transpose Wh into ws:  wt[d][k][g] = Wh_d[g][k]
// ---------------------------------------------------------------------------
__global__ void transpose_wh(const float* __restrict__ Whf,
                             const float* __restrict__ Whb,
                             float* __restrict__ wt)
{
    int g = blockIdx.x * 256 + threadIdx.x;   // 0..767 (grid.x = 3)
    int k = blockIdx.y;                        // 0..255
    int d = blockIdx.z;                        // 0..1
    const float* W = d ? Whb : Whf;
    wt[((size_t)d * II + k) * GG + g] = W[(size_t)g * II + k];
}

// ---------------------------------------------------------------------------
// Kernel B: gi[d][b][t][g] = x[b,t,:] @ Wi_d[g,:] + bi_d[g]
// M = 2*B*T = 65536 rows (m = d*32768 + b*512 + t), N = 768, K = 256
// ---------------------------------------------------------------------------
__global__ __launch_bounds__(256) void gi_gemm(
    const float* __restrict__ x,
    const float* __restrict__ Wif, const float* __restrict__ bif,
    const float* __restrict__ Wib, const float* __restrict__ bib,
    float* __restrict__ gi)
{
    const int KC = 16;
    __shared__ float As[64][KC + 1];
    __shared__ float Bs[64][KC + 1];

    const int m0 = blockIdx.x * 64;
    const int n0 = blockIdx.y * 64;
    const int d  = m0 >> 15;
    const float* __restrict__ W    = d ? Wib : Wif;
    const float* __restrict__ bias = d ? bib : bif;

    const int tid = threadIdx.x;
    const int tx = tid & 15, ty = tid >> 4;
    const int xrow = m0 & 32767;

    const int le = tid * 4;
    const int lr = le >> 4;
    const int lk = le & 15;

    float acc[4][4] = {};

    for (int k0 = 0; k0 < II; k0 += KC) {
        float4 av = *(const float4*)&x[(size_t)(xrow + lr) * II + (k0 + lk)];
        float4 bv = *(const float4*)&W[(size_t)(n0 + lr) * II + (k0 + lk)];
        As[lr][lk + 0] = av.x; As[lr][lk + 1] = av.y; As[lr][lk + 2] = av.z; As[lr][lk + 3] = av.w;
        Bs[lr][lk + 0] = bv.x; Bs[lr][lk + 1] = bv.y; Bs[lr][lk + 2] = bv.z; Bs[lr][lk + 3] = bv.w;
        __syncthreads();
#pragma unroll
        for (int kk = 0; kk < KC; ++kk) {
            float a[4], b[4];
#pragma unroll
            for (int i = 0; i < 4; ++i) a[i] = As[ty * 4 + i][kk];
#pragma unroll
            for (int j = 0; j < 4; ++j) b[j] = Bs[tx * 4 + j][kk];
#pragma unroll
            for (int i = 0; i < 4; ++i)
#pragma unroll
                for (int j = 0; j < 4; ++j) acc[i][j] += a[i] * b[j];
        }
        __syncthreads();
    }

#pragma unroll
    for (int i = 0; i < 4; ++i) {
        float4 o;
        o.x = acc[i][0] + bias[n0 + tx * 4 + 0];
        o.y = acc[i][1] + bias[n0 + tx * 4 + 1];
        o.z = acc[i][2] + bias[n0 + tx * 4 + 2];
        o.w = acc[i][3] + bias[n0 + tx * 4 + 3];
        *(float4*)&gi[(size_t)(m0 + ty * 4 + i) * GG + n0 + tx * 4] = o;
    }
}

// ---------------------------------------------------------------------------
// Kernel C: the sequential scan. One workgroup per (direction, batch) chain.
// 768 threads: thread g computes gate-row g; threads <256 do gate math.
// PRECOMP: gi from ws, weights from transposed WhT (coalesced).
// !PRECOMP: everything on the fly from row-major weights (fallback).
// ---------------------------------------------------------------------------
template <bool PRECOMP>
__global__ __launch_bounds__(768) void gru_scan_k(
    const float* __restrict__ x,
    const float* __restrict__ gi,     // [2][B][T][G] (PRECOMP only)
    const float* __restrict__ wt,     // [2][K=256][G=768] (PRECOMP only)
    const float* __restrict__ h0f, const float* __restrict__ h0b,
    const float* __restrict__ Wif, const float* __restrict__ bif_,
    const float* __restrict__ Whf, const float* __restrict__ bhf,
    const float* __restrict__ Wib, const float* __restrict__ bib_,
    const float* __restrict__ Whb, const float* __restrict__ bhb,
    float* __restrict__ out)
{
    __shared__ __align__(16) float hbuf[2][HH];
    __shared__ float gh_s[GG];
    __shared__ float gi_s[GG];
    __shared__ __align__(16) float xrow[II];

    const int bx  = blockIdx.x;
    const int d   = bx >> 6;
    const int b   = bx & 63;
    const int tid = threadIdx.x;

    const float* __restrict__ Wh = d ? Whb : Whf;
    const float* __restrict__ bh = d ? bhb : bhf;
    const float* __restrict__ Wi = d ? Wib : Wif;
    const float* __restrict__ bi = d ? bib_ : bif_;
    const float* __restrict__ h0 = d ? h0b : h0f;

    if (tid < HH) hbuf[0][tid] = h0[(size_t)b * HH + tid];

    const float bh_row = bh[tid];
    const float bi_row = bi[tid];
    const float* __restrict__ wtd = PRECOMP ? (wt + (size_t)d * II * GG) : nullptr;
    const float4* __restrict__ whr = (const float4*)(Wh + (size_t)tid * II);
    const float4* __restrict__ wir = (const float4*)(Wi + (size_t)tid * II);
    const size_t gibase0 = ((size_t)d * BB + b) * (size_t)TT * GG;

    __syncthreads();

    for (int s = 0; s < TT; ++s) {
        const int ta  = d ? (TT - 1 - s) : s;
        const int cur = s & 1;

        if (!PRECOMP) {
            if (tid < II) xrow[tid] = x[((size_t)b * TT + ta) * II + tid];
            __syncthreads();
        }

        // gh row `tid` = dot(h, Wh[tid,:]) + bh[tid]
        if (PRECOMP) {
            const float4* hv4 = (const float4*)hbuf[cur];
            float a0 = 0.f, a1 = 0.f, a2 = 0.f, a3 = 0.f;
#pragma unroll 4
            for (int k = 0; k < II; k += 4) {
                float4 h4 = hv4[k >> 2];
                a0 += h4.x * wtd[(size_t)(k + 0) * GG + tid];
                a1 += h4.y * wtd[(size_t)(k + 1) * GG + tid];
                a2 += h4.z * wtd[(size_t)(k + 2) * GG + tid];
                a3 += h4.w * wtd[(size_t)(k + 3) * GG + tid];
            }
            gh_s[tid] = (a0 + a1) + (a2 + a3) + bh_row;
        } else {
            const float4* hv4 = (const float4*)hbuf[cur];
            float a0 = 0.f, a1 = 0.f, a2 = 0.f, a3 = 0.f;
#pragma unroll 4
            for (int k = 0; k < II / 4; k += 4) {
                float4 w0 = whr[k], w1 = whr[k + 1], w2 = whr[k + 2], w3 = whr[k + 3];
                float4 q0 = hv4[k], q1 = hv4[k + 1], q2 = hv4[k + 2], q3 = hv4[k + 3];
                a0 += w0.x * q0.x + w0.y * q0.y + w0.z * q0.z + w0.w * q0.w;
                a1 += w1.x * q1.x + w1.y * q1.y + w1.z * q1.z + w1.w * q1.w;
                a2 += w2.x * q2.x + w2.y * q2.y + w2.z * q2.z + w2.w * q2.w;
                a3 += w3.x * q3.x + w3.y * q3.y + w3.z * q3.z + w3.w * q3.w;
            }
            gh_s[tid] = (a0 + a1) + (a2 + a3) + bh_row;

            const float4* xv4 = (const float4*)xrow;
            float c0 = 0.f, c1 = 0.f, c2 = 0.f, c3 = 0.f;
#pragma unroll 4
            for (int k = 0; k < II / 4; k += 4) {
                float4 w0 = wir[k], w1 = wir[k + 1], w2 = wir[k + 2], w3 = wir[k + 3];
                float4 q0 = xv4[k], q1 = xv4[k + 1], q2 = xv4[k + 2], q3 = xv4[k + 3];
                c0 += w0.x * q0.x + w0.y * q0.y + w0.z * q0.z + w0.w * q0.w;
                c1 += w1.x * q1.x + w1.y * q1.y + w1.z * q1.z + w1.w * q1.w;
                c2 += w2.x * q2.x + w2.y * q2.y + w2.z * q2.z + w2.w * q2.w;
                c3 += w3.x * q3.x + w3.y * q3.y + w3.z * q3.z + w3.w * q3.w;
            }
            gi_s[tid] = (c0 + c1) + (c2 + c3) + bi_row;
        }
        __syncthreads();

        if (tid < HH) {
            float ir, iz, inn;
            if (PRECOMP) {
                const float* g = gi + gibase0 + (size_t)ta * GG;
                ir = g[tid]; iz = g[HH + tid]; inn = g[2 * HH + tid];
            } else {
                ir = gi_s[tid]; iz = gi_s[HH + tid]; inn = gi_s[2 * HH + tid];
            }
            float hr = gh_s[tid], hz = gh_s[HH + tid], hn = gh_s[2 * HH + tid];
            float r  = sigf(ir + hr);
            float z  = sigf(iz + hz);
            float n  = tanh_fast(inn + r * hn);
            float hp = hbuf[cur][tid];
            float hnew = tanh_fast((1.f - z) * n + z * hp);
            hbuf[cur ^ 1][tid] = hnew;
            out[((size_t)b * TT + ta) * (2 * HH) + d * HH + tid] = hnew;
        }
        __syncthreads();
    }
}

// ---------------------------------------------------------------------------
extern "C" void kernel_launch(void* const* d_in, const int* in_sizes, int n_in,
                              void* d_out, int out_size, void* d_ws, size_t ws_size,
                              hipStream_t stream)
{
    const float* x   = (const float*)d_in[0];
    const float* h0f = (const float*)d_in[1];
    const float* h0b = (const float*)d_in[2];
    const float* Wif = (const float*)d_in[3];
    const float* Whf = (const float*)d_in[4];
    const float* bif = (const float*)d_in[5];
    const float* bhf = (const float*)d_in[6];
    const float* Wib = (const float*)d_in[7];
    const float* Whb = (const float*)d_in[8];
    const float* bib = (const float*)d_in[9];
    const float* bhb = (const float*)d_in[10];
    float* out = (float*)d_out;

    const size_t gi_bytes = (size_t)2 * BB * TT * GG * sizeof(float);   // 201,326,592
    const size_t wt_bytes = (size_t)2 * II * GG * sizeof(float);        //   1,572,864

    if (ws_size >= gi_bytes + wt_bytes) {
        float* gi = (float*)d_ws;
        float* wt = (float*)((char*)d_ws + gi_bytes);

        dim3 tg(3, 256, 2);
        transpose_wh<<<tg, 256, 0, stream>>>(Whf, Whb, wt);

        dim3 gg(1024, 12);
        gi_gemm<<<gg, 256, 0, stream>>>(x, Wif, bif, Wib, bib, gi);

        gru_scan_k<true><<<128, 768, 0, stream>>>(
            x, gi, wt, h0f, h0b, Wif, bif, Whf, bhf, Wib, bib, Whb, bhb, out);
    } else {
        gru_scan_k<false><<<128, 768, 0, stream>>>(
            x, nullptr, nullptr, h0f, h0b, Wif, bif, Whf, bhf, Wib, bib, Whb, bhb, out);
    }
}